// Round 6
// baseline (243.154 us; speedup 1.0000x reference)
//
#include <hip/hip_runtime.h>

// Problem constants (CausalAttention: B=4, S=2048, D_IN=D_OUT=1024, single head)
#define Bb 4
#define Ss 2048
#define Dd 1024

typedef unsigned short u16;
typedef __bf16 bf16x8 __attribute__((ext_vector_type(8)));
typedef float  f32x4  __attribute__((ext_vector_type(4)));

__device__ inline u16 f2bf(float f) {
  union { float f; unsigned u; } x; x.f = f;
  unsigned u = x.u;
  return (u16)((u + 0x7fffu + ((u >> 16) & 1u)) >> 16);  // RNE
}
__device__ inline float bf2f(u16 h) {
  union { unsigned u; float f; } x; x.u = ((unsigned)h) << 16;
  return x.f;
}

// async global->LDS, 16B per lane. LDS dest is wave-uniform base + lane*16:
// lane order must match LDS contiguity.
__device__ static inline void gl_lds16(const u16* g, u16* l) {
  __builtin_amdgcn_global_load_lds((__attribute__((address_space(1))) const void*)g,
                                   (__attribute__((address_space(3))) void*)l,
                                   16, 0, 0);
}

// ---------------- cast fp32 -> bf16 (x + 3 weights) + lsum zeroing ----------------
__global__ __launch_bounds__(256) void cast_all(const float* __restrict__ x,
                                                const float* __restrict__ wq,
                                                const float* __restrict__ wk,
                                                const float* __restrict__ wv,
                                                u16* __restrict__ xb,
                                                u16* __restrict__ wb,
                                                float* __restrict__ lsum) {
  int id = blockIdx.x;
  if (id < 8) {
    float4 z = {0.f, 0.f, 0.f, 0.f};
    ((float4*)lsum)[id * 256 + threadIdx.x] = z;
  }
  const float* src; u16* dst; int off;
  if (id < 2048) {                      // x: 8M elements
    src = x; dst = xb; off = id * 4096;
  } else {                              // weights: 1M each, 256 blocks per W
    int wi = id - 2048;
    int w = wi >> 8;
    src = (w == 0) ? wq : (w == 1) ? wk : wv;
    dst = wb + (size_t)w * Dd * Dd;
    off = (wi & 255) * 4096;
  }
#pragma unroll
  for (int t = 0; t < 4; t++) {
    int i = off + t * 1024 + threadIdx.x * 4;
    float4 v = *(const float4*)(src + i);
    unsigned p0 = (unsigned)f2bf(v.x) | ((unsigned)f2bf(v.y) << 16);
    unsigned p1 = (unsigned)f2bf(v.z) | ((unsigned)f2bf(v.w) << 16);
    uint2 p; p.x = p0; p.y = p1;
    *(uint2*)(dst + i) = p;
  }
}

// ---------------- shared GEMM core (C = A * B^T), bf16 in, fp32 acc ----------------
// BK=64 per barrier-pair via two BK=32 LDS buffer pairs (one vmcnt(0)+barrier
// drain per 64-K). lds: lA0|lB0|lA1|lB1, each 4096 u16 (128 rows x 32, unpadded).
#define BM 128
#define BN 128

__device__ inline void gemm_tile(const u16* __restrict__ A, int lda,
                                 const u16* __restrict__ Bp, int ldb,
                                 int kBeg, int kEnd,  // multiples of 64
                                 u16* lds, f32x4 acc[4][4]) {
  u16* lA0 = lds;
  u16* lB0 = lds + 4096;
  u16* lA1 = lds + 8192;
  u16* lB1 = lds + 12288;
  const int tid  = threadIdx.x;
  const int lane = tid & 63, wave = tid >> 6;
  const int quad = lane >> 4, r16 = lane & 15;
  const int wm = (wave & 1) * 64, wn = (wave >> 1) * 64;
  const int r0 = tid >> 2, part = tid & 3;  // seg s=q*256+tid -> row=q*64+r0

  for (int k0 = kBeg; k0 < kEnd; k0 += 64) {
    __syncthreads();  // previous halves' ds_reads done before overwrite
#pragma unroll
    for (int q = 0; q < 2; q++) {
      int row = q * 64 + r0;
      int s8 = (q * 256 + tid) * 8;
      const u16* ga = A  + (size_t)row * lda + k0 + part * 8;
      const u16* gb = Bp + (size_t)row * ldb + k0 + part * 8;
      gl_lds16(ga,      lA0 + s8);
      gl_lds16(gb,      lB0 + s8);
      gl_lds16(ga + 32, lA1 + s8);
      gl_lds16(gb + 32, lB1 + s8);
    }
    __syncthreads();
#pragma unroll
    for (int h = 0; h < 2; h++) {
      const u16* la = h ? lA1 : lA0;
      const u16* lb = h ? lB1 : lB0;
      bf16x8 fa[4], fb[4];
#pragma unroll
      for (int t = 0; t < 4; t++)
        fa[t] = *(const bf16x8*)(la + (wm + t * 16 + r16) * 32 + quad * 8);
#pragma unroll
      for (int t = 0; t < 4; t++)
        fb[t] = *(const bf16x8*)(lb + (wn + t * 16 + r16) * 32 + quad * 8);
#pragma unroll
      for (int tm = 0; tm < 4; tm++)
#pragma unroll
        for (int tn = 0; tn < 4; tn++)
          acc[tm][tn] = __builtin_amdgcn_mfma_f32_16x16x32_bf16(fa[tm], fb[tn],
                                                                acc[tm][tn], 0, 0, 0);
    }
  }
}

// ---------------- QKV projection, XCD-swizzled 1-D grid ----------------
// z==0/1 (Q,K): normal [row, col] bf16 store.
// z==2 (V): writes vt[b, e, s] DIRECTLY via in-LDS 128x128 transpose
// (v-normal layout is never consumed; saves the separate transpose kernel).
__global__ __launch_bounds__(256) void qkv_gemm(const u16* __restrict__ xb,
                                                const u16* __restrict__ wb,
                                                u16* __restrict__ qk,
                                                u16* __restrict__ vt) {
  __shared__ __align__(16) u16 shmem[16384];
  const int id  = blockIdx.x;          // 0..1535
  const int xcd = id & 7, j = id >> 3; // j 0..191
  const int xt  = j & 7;               // col tile (fastest within XCD)
  const int yl  = (j >> 3) & 7;
  const int zi  = j >> 6;              // 0..2
  const int y   = xcd * 8 + yl;        // row tile 0..63
  const int row0 = y * BM;             // M = B*S = 8192
  const int col0 = xt * BN;            // N = 1024
  const u16* A  = xb + (size_t)row0 * Dd;
  const u16* Bp = wb + (size_t)zi * Dd * Dd + (size_t)col0 * Dd;
  f32x4 acc[4][4];
  const f32x4 zero = {0.f, 0.f, 0.f, 0.f};
#pragma unroll
  for (int tm = 0; tm < 4; tm++)
#pragma unroll
    for (int tn = 0; tn < 4; tn++) acc[tm][tn] = zero;

  gemm_tile(A, Dd, Bp, Dd, 0, Dd, shmem, acc);

  const int tid = threadIdx.x;
  const int lane = tid & 63, wave = tid >> 6;
  const int quad = lane >> 4, r16 = lane & 15;
  const int wm = (wave & 1) * 64, wn = (wave >> 1) * 64;

  if (zi < 2) {
    u16* out = qk + (size_t)zi * ((size_t)Bb * Ss * Dd);
#pragma unroll
    for (int tm = 0; tm < 4; tm++)
#pragma unroll
      for (int tn = 0; tn < 4; tn++) {
        int rr = row0 + wm + tm * 16 + quad * 4;
        int cc = col0 + wn + tn * 16 + r16;
#pragma unroll
        for (int r = 0; r < 4; r++)
          out[(size_t)(rr + r) * Dd + cc] = f2bf(acc[tm][tn][r]);
      }
    return;
  }

  // ---- V: transpose epilogue. Tile rows = s (within one b), cols = e. ----
  const int b = row0 >> 11, srow = row0 & 2047;
  u16* vtb = vt + (size_t)b * Dd * Ss;
  // two passes of 64 e-columns; lds layout [e_rel][s] stride 136 (pad 8)
#pragma unroll
  for (int p = 0; p < 2; p++) {
    __syncthreads();  // lds free (gemm reads done / previous pass consumed)
    if ((wave >> 1) == p) {  // waves holding cols [p*64, p*64+64)
#pragma unroll
      for (int tm = 0; tm < 4; tm++)
#pragma unroll
        for (int tn = 0; tn < 4; tn++) {
          int cl = tn * 16 + r16;            // 0..63 within pass
          int rr4 = wm + tm * 16 + quad * 4; // 0..124, mult of 4
          u16 pk[4];
#pragma unroll
          for (int r = 0; r < 4; r++) pk[r] = f2bf(acc[tm][tn][r]);
          *(uint2*)(shmem + cl * 136 + rr4) = *(const uint2*)pk;
        }
    }
    __syncthreads();
    // all 256 threads: row e_rel = tid>>2, s-chunk (tid&3)*32 -> 64B pieces
    const u16* lr_ = shmem + (tid >> 2) * 136 + (tid & 3) * 32;
    u16* gp = vtb + (size_t)(col0 + p * 64 + (tid >> 2)) * Ss + srow + (tid & 3) * 32;
#pragma unroll
    for (int jj = 0; jj < 4; jj++)
      *(uint4*)(gp + jj * 8) = *(const uint4*)(lr_ + jj * 8);
  }
}

// ---------------- scores + rowsum: sc = exp(QK^T/32), lower tiles, diag masked ----
__global__ __launch_bounds__(256) void scores_kernel(const u16* __restrict__ qb,
                                                     const u16* __restrict__ kb,
                                                     u16* __restrict__ sc,
                                                     float* __restrict__ lsum) {
  __shared__ __align__(16) u16 shmem[16384];
  const int id = blockIdx.x;   // 0..543
  const int tid = threadIdx.x;
  // XCD swizzle: 17 consecutive tri-ids per XCD per batch (136 = 8*17).
  const int xcd = id & 7, j = id >> 3;   // j 0..67
  const int b = j / 17, tloc = j - b * 17;
  const int t = xcd * 17 + tloc;         // 0..135 lower-tri index
  int it = (int)((sqrtf(8.f * (float)t + 1.f) - 1.f) * 0.5f);
  while ((it + 1) * (it + 2) / 2 <= t) it++;
  while (it * (it + 1) / 2 > t) it--;
  const int jt = t - it * (it + 1) / 2;

  const u16* A  = qb + (size_t)b * Ss * Dd + (size_t)it * BM * Dd;
  const u16* Bp = kb + (size_t)b * Ss * Dd + (size_t)jt * BN * Dd;
  f32x4 acc[4][4];
  const f32x4 zero = {0.f, 0.f, 0.f, 0.f};
#pragma unroll
  for (int tm = 0; tm < 4; tm++)
#pragma unroll
    for (int tn = 0; tn < 4; tn++) acc[tm][tn] = zero;

  gemm_tile(A, Dd, Bp, Dd, 0, Dd, shmem, acc);

  // Unnormalized exp (|s/32| << 88 so fp32 exp safe without max-subtraction).
  u16* out = sc + (size_t)b * Ss * Ss;
  float* lr = lsum + (size_t)b * Ss;
  const int lane = tid & 63, wave = tid >> 6;
  const int quad = lane >> 4, r16 = lane & 15;
  const int wm = (wave & 1) * 64, wn = (wave >> 1) * 64;
#pragma unroll
  for (int tm = 0; tm < 4; tm++) {
    float psum[4] = {0.f, 0.f, 0.f, 0.f};  // per r, summed over tn
#pragma unroll
    for (int tn = 0; tn < 4; tn++) {
      int rr = it * BM + wm + tm * 16 + quad * 4;
      int cc = jt * BN + wn + tn * 16 + r16;
#pragma unroll
      for (int r = 0; r < 4; r++) {
        float p = 0.f;
        u16 h = 0;
        if (cc <= rr + r) {
          h = f2bf(__expf(acc[tm][tn][r] * 0.03125f));
          p = bf2f(h);  // sum the bf16-rounded value (matches stored numerator)
        }
        out[(size_t)(rr + r) * Ss + cc] = h;
        psum[r] += p;
      }
    }
#pragma unroll
    for (int r = 0; r < 4; r++) {
      float s = psum[r];
      s += __shfl_xor(s, 1);
      s += __shfl_xor(s, 2);
      s += __shfl_xor(s, 4);
      s += __shfl_xor(s, 8);
      if (r16 == 0) {
        int row = it * BM + wm + tm * 16 + quad * 4 + r;
        atomicAdd(&lr[row], s);
      }
    }
  }
}

// ---------------- PV: O[q,e] = (1/l[q]) * sum_k sc[q,k] Vt[e,k] ----------------
// Pairing-robust schedule: s=idx&7 (=XCD), half=idx>>8, it = half ? s : 15-s.
// Every XCD gets exactly 544 tile-K (uniform regardless of block->CU pairing);
// under spread-first mapping CU pairs (idx, idx+256) get complementary halves
// -> uniform 17 tile-K per CU.
__global__ __launch_bounds__(256) void pv_gemm(const u16* __restrict__ sc,
                                               const u16* __restrict__ vt,
                                               const float* __restrict__ lsum,
                                               float* __restrict__ out) {
  __shared__ __align__(16) u16 shmem[16384];
  const int idx = blockIdx.x;            // 0..511
  const int sp = idx & 7;
  const int bc = (idx >> 3) & 31;
  const int half = idx >> 8;
  const int it = half ? sp : (15 - sp);
  const int b = bc >> 3;
  const int col0 = (bc & 7) * BN;        // N = 1024
  const int row0 = it * BM;
  const u16* A  = sc + (size_t)b * Ss * Ss + (size_t)row0 * Ss;
  const u16* Bp = vt + (size_t)b * Dd * Ss + (size_t)col0 * Ss;
  f32x4 acc[4][4];
  const f32x4 zero = {0.f, 0.f, 0.f, 0.f};
#pragma unroll
  for (int tm = 0; tm < 4; tm++)
#pragma unroll
    for (int tn = 0; tn < 4; tn++) acc[tm][tn] = zero;

  // causal: P[q,k]==0 for k > q (incl. zero-filled diag tile), K-loop clipped
  gemm_tile(A, Ss, Bp, Ss, 0, row0 + BM, shmem, acc);

  float* o = out + (size_t)b * Ss * Dd;
  const float* lr = lsum + (size_t)b * Ss;
  const int lane = threadIdx.x & 63, wave = threadIdx.x >> 6;
  const int quad = lane >> 4, r16 = lane & 15;
  const int wm = (wave & 1) * 64, wn = (wave >> 1) * 64;
#pragma unroll
  for (int tm = 0; tm < 4; tm++) {
    int rbase = row0 + wm + tm * 16 + quad * 4;
    float s0 = 1.f / lr[rbase], s1 = 1.f / lr[rbase + 1];
    float s2 = 1.f / lr[rbase + 2], s3 = 1.f / lr[rbase + 3];
#pragma unroll
    for (int tn = 0; tn < 4; tn++) {
      int cc = col0 + wn + tn * 16 + r16;
      o[(size_t)(rbase + 0) * Dd + cc] = acc[tm][tn][0] * s0;
      o[(size_t)(rbase + 1) * Dd + cc] = acc[tm][tn][1] * s1;
      o[(size_t)(rbase + 2) * Dd + cc] = acc[tm][tn][2] * s2;
      o[(size_t)(rbase + 3) * Dd + cc] = acc[tm][tn][3] * s3;
    }
  }
}

// ---------------- launch ----------------
// Workspace layout (bytes), total 106,987,520 (~102 MB):
//   qk  : [0, 33554432)           q,k bf16, 16 MB each
//   vt  : [33554432, 50331648)    V^T bf16 [b,e,s] (written by qkv z==2)
//   sc  : [50331648, 83886080)    exp-scores bf16, 32 MB
//   xb  : [83886080, 100663296)   x bf16 16 MB (live through qkv_gemm)
//   wb  : [100663296, 106954752)  wq|wk|wv bf16, 6 MB
//   lsum: [106954752, 106987520)  per-row sum fp32, 32 KB (zeroed by cast_all)
extern "C" void kernel_launch(void* const* d_in, const int* in_sizes, int n_in,
                              void* d_out, int out_size, void* d_ws, size_t ws_size,
                              hipStream_t stream) {
  const float* x  = (const float*)d_in[0];
  const float* wq = (const float*)d_in[1];
  const float* wk = (const float*)d_in[2];
  const float* wv = (const float*)d_in[3];
  float* out = (float*)d_out;
  char* ws = (char*)d_ws;
  if (ws_size < 106987520u) return;  // clean fail rather than OOB corruption

  u16* qk   = (u16*)(ws);
  u16* vt   = (u16*)(ws + 33554432u);
  u16* sc   = (u16*)(ws + 50331648u);
  u16* xb   = (u16*)(ws + 83886080u);
  u16* wb   = (u16*)(ws + 100663296u);
  float* lsum = (float*)(ws + 106954752u);

  const size_t nQ = (size_t)Bb * Ss * Dd;  // 8388608

  cast_all<<<2816, 256, 0, stream>>>(x, wq, wk, wv, xb, wb, lsum);
  qkv_gemm<<<1536, 256, 0, stream>>>(xb, wb, qk, vt);
  scores_kernel<<<544, 256, 0, stream>>>(qk, qk + nQ, sc, lsum);
  pv_gemm<<<512, 256, 0, stream>>>(sc, vt, lsum, out);
}

// Round 8
// 237.016 us; speedup vs baseline: 1.0259x; 1.0259x over previous
//
#include <hip/hip_runtime.h>

// Problem constants (CausalAttention: B=4, S=2048, D_IN=D_OUT=1024, single head)
#define Bb 4
#define Ss 2048
#define Dd 1024

typedef unsigned short u16;
typedef __bf16 bf16x8 __attribute__((ext_vector_type(8)));
typedef float  f32x4  __attribute__((ext_vector_type(4)));

__device__ inline u16 f2bf(float f) {
  union { float f; unsigned u; } x; x.f = f;
  unsigned u = x.u;
  return (u16)((u + 0x7fffu + ((u >> 16) & 1u)) >> 16);  // RNE
}
__device__ inline float bf2f(u16 h) {
  union { unsigned u; float f; } x; x.u = ((unsigned)h) << 16;
  return x.f;
}

// async global->LDS, 16B per lane. LDS dest is wave-uniform base + lane*16:
// lane order must match LDS contiguity.
__device__ static inline void gl_lds16(const u16* g, u16* l) {
  __builtin_amdgcn_global_load_lds((__attribute__((address_space(1))) const void*)g,
                                   (__attribute__((address_space(3))) void*)l,
                                   16, 0, 0);
}

// ---------------- cast fp32 -> bf16 (x + 3 weights) + lsum zeroing ----------------
__global__ __launch_bounds__(256) void cast_all(const float* __restrict__ x,
                                                const float* __restrict__ wq,
                                                const float* __restrict__ wk,
                                                const float* __restrict__ wv,
                                                u16* __restrict__ xb,
                                                u16* __restrict__ wb,
                                                float* __restrict__ lsum) {
  int id = blockIdx.x;
  if (id < 8) {
    float4 z = {0.f, 0.f, 0.f, 0.f};
    ((float4*)lsum)[id * 256 + threadIdx.x] = z;
  }
  const float* src; u16* dst; int off;
  if (id < 2048) {                      // x: 8M elements
    src = x; dst = xb; off = id * 4096;
  } else {                              // weights: 1M each, 256 blocks per W
    int wi = id - 2048;
    int w = wi >> 8;
    src = (w == 0) ? wq : (w == 1) ? wk : wv;
    dst = wb + (size_t)w * Dd * Dd;
    off = (wi & 255) * 4096;
  }
#pragma unroll
  for (int t = 0; t < 4; t++) {
    int i = off + t * 1024 + threadIdx.x * 4;
    float4 v = *(const float4*)(src + i);
    unsigned p0 = (unsigned)f2bf(v.x) | ((unsigned)f2bf(v.y) << 16);
    unsigned p1 = (unsigned)f2bf(v.z) | ((unsigned)f2bf(v.w) << 16);
    uint2 p; p.x = p0; p.y = p1;
    *(uint2*)(dst + i) = p;
  }
}

// ---------------- shared GEMM core (C = A * B^T), bf16 in, fp32 acc ----------------
// BK=64 per barrier-pair via two BK=32 LDS buffer pairs (one vmcnt(0)+barrier
// drain per 64-K). lds: lA0|lB0|lA1|lB1, each 4096 u16 (128 rows x 32, unpadded).
#define BM 128
#define BN 128

__device__ inline void gemm_tile(const u16* __restrict__ A, int lda,
                                 const u16* __restrict__ Bp, int ldb,
                                 int kBeg, int kEnd,  // multiples of 64
                                 u16* lds, f32x4 acc[4][4]) {
  u16* lA0 = lds;
  u16* lB0 = lds + 4096;
  u16* lA1 = lds + 8192;
  u16* lB1 = lds + 12288;
  const int tid  = threadIdx.x;
  const int lane = tid & 63, wave = tid >> 6;
  const int quad = lane >> 4, r16 = lane & 15;
  const int wm = (wave & 1) * 64, wn = (wave >> 1) * 64;
  const int r0 = tid >> 2, part = tid & 3;  // seg s=q*256+tid -> row=q*64+r0

  for (int k0 = kBeg; k0 < kEnd; k0 += 64) {
    __syncthreads();  // previous halves' ds_reads done before overwrite
#pragma unroll
    for (int q = 0; q < 2; q++) {
      int row = q * 64 + r0;
      int s8 = (q * 256 + tid) * 8;
      const u16* ga = A  + (size_t)row * lda + k0 + part * 8;
      const u16* gb = Bp + (size_t)row * ldb + k0 + part * 8;
      gl_lds16(ga,      lA0 + s8);
      gl_lds16(gb,      lB0 + s8);
      gl_lds16(ga + 32, lA1 + s8);
      gl_lds16(gb + 32, lB1 + s8);
    }
    __syncthreads();
#pragma unroll
    for (int h = 0; h < 2; h++) {
      const u16* la = h ? lA1 : lA0;
      const u16* lb = h ? lB1 : lB0;
      bf16x8 fa[4], fb[4];
#pragma unroll
      for (int t = 0; t < 4; t++)
        fa[t] = *(const bf16x8*)(la + (wm + t * 16 + r16) * 32 + quad * 8);
#pragma unroll
      for (int t = 0; t < 4; t++)
        fb[t] = *(const bf16x8*)(lb + (wn + t * 16 + r16) * 32 + quad * 8);
#pragma unroll
      for (int tm = 0; tm < 4; tm++)
#pragma unroll
        for (int tn = 0; tn < 4; tn++)
          acc[tm][tn] = __builtin_amdgcn_mfma_f32_16x16x32_bf16(fa[tm], fb[tn],
                                                                acc[tm][tn], 0, 0, 0);
    }
  }
}

// ---------------- QKV projection, XCD-swizzled 1-D grid (thin epilogue) ------------
// id%8 = XCD. Each XCD gets a fixed 8-row-tile stripe of A x all B tiles
// -> per-XCD L2 working set ~6 MB (FETCH 135->49 MB measured r4).
__global__ __launch_bounds__(256) void qkv_gemm(const u16* __restrict__ xb,
                                                const u16* __restrict__ wb,
                                                u16* __restrict__ qkv) {
  __shared__ __align__(16) u16 shmem[16384];
  const int id  = blockIdx.x;          // 0..1535
  const int xcd = id & 7, j = id >> 3; // j 0..191
  const int xt  = j & 7;               // col tile (fastest within XCD)
  const int yl  = (j >> 3) & 7;
  const int zi  = j >> 6;              // 0..2
  const int y   = xcd * 8 + yl;        // row tile 0..63
  const int row0 = y * BM;             // M = B*S = 8192
  const int col0 = xt * BN;            // N = 1024
  const u16* A  = xb + (size_t)row0 * Dd;
  const u16* Bp = wb + (size_t)zi * Dd * Dd + (size_t)col0 * Dd;
  f32x4 acc[4][4];
  const f32x4 zero = {0.f, 0.f, 0.f, 0.f};
#pragma unroll
  for (int tm = 0; tm < 4; tm++)
#pragma unroll
    for (int tn = 0; tn < 4; tn++) acc[tm][tn] = zero;

  gemm_tile(A, Dd, Bp, Dd, 0, Dd, shmem, acc);

  u16* out = qkv + (size_t)zi * ((size_t)Bb * Ss * Dd);
  const int lane = threadIdx.x & 63, wave = threadIdx.x >> 6;
  const int quad = lane >> 4, r16 = lane & 15;
  const int wm = (wave & 1) * 64, wn = (wave >> 1) * 64;
#pragma unroll
  for (int tm = 0; tm < 4; tm++)
#pragma unroll
    for (int tn = 0; tn < 4; tn++) {
      int rr = row0 + wm + tm * 16 + quad * 4;
      int cc = col0 + wn + tn * 16 + r16;
#pragma unroll
      for (int r = 0; r < 4; r++)
        out[(size_t)(rr + r) * Dd + cc] = f2bf(acc[tm][tn][r]);
    }
}

// ---------------- fused scores + rowsum + V-transpose ----------------
// Blocks [0,544): lower-tri score tiles -> sc = exp(QK^T/32) (diag masked),
//   per-row partial sums atomically added into lsum (bf16-rounded p summed so
//   numerator/denominator rounding match).
// Blocks [544,1024): V transpose, grid-stride over 2048 64x64 tiles.
__global__ __launch_bounds__(256) void scores_fused(const u16* __restrict__ qb,
                                                    const u16* __restrict__ kb,
                                                    const u16* __restrict__ vb,
                                                    u16* __restrict__ sc,
                                                    u16* __restrict__ vt,
                                                    float* __restrict__ lsum) {
  __shared__ __align__(16) u16 shmem[16384];
  const int id = blockIdx.x;
  const int tid = threadIdx.x;

  if (id >= 544) {  // ---- transpose role ----
    const int bid = id - 544;            // 0..479
    u16 (*t)[72] = (u16(*)[72])shmem;    // 64x72 u16 = 9216 <= 16384
    for (int u = bid; u < 2048; u += 480) {
      const int b = u >> 9, rem = u & 511;
      const int e0 = (rem >> 5) * 64, s0 = (rem & 31) * 64;
      const u16* src = vb + (size_t)b * Ss * Dd;
      u16* dst = vt + (size_t)b * Dd * Ss;
      if (u != bid) __syncthreads();
#pragma unroll
      for (int gg = tid; gg < 512; gg += 256) {
        int row = gg >> 3, prt = gg & 7;
        uint4 v = *(const uint4*)(src + (size_t)(s0 + row) * Dd + e0 + prt * 8);
        const u16* pv = (const u16*)&v;
#pragma unroll
        for (int jj = 0; jj < 8; jj++) t[prt * 8 + jj][row] = pv[jj];
      }
      __syncthreads();
#pragma unroll
      for (int gg = tid; gg < 512; gg += 256) {
        int ee = gg >> 3, prt = gg & 7;
        uint4 v = *(const uint4*)(&t[ee][prt * 8]);
        *(uint4*)(dst + (size_t)(e0 + ee) * Ss + s0 + prt * 8) = v;
      }
    }
    return;
  }

  // ---- scores role ----
  // XCD swizzle: 17 consecutive tri-ids per XCD per batch (136 = 8*17).
  const int xcd = id & 7, j = id >> 3;   // j 0..67
  const int b = j / 17, tloc = j - b * 17;
  const int t = xcd * 17 + tloc;         // 0..135 lower-tri index
  int it = (int)((sqrtf(8.f * (float)t + 1.f) - 1.f) * 0.5f);
  while ((it + 1) * (it + 2) / 2 <= t) it++;
  while (it * (it + 1) / 2 > t) it--;
  const int jt = t - it * (it + 1) / 2;

  const u16* A  = qb + (size_t)b * Ss * Dd + (size_t)it * BM * Dd;
  const u16* Bp = kb + (size_t)b * Ss * Dd + (size_t)jt * BN * Dd;
  f32x4 acc[4][4];
  const f32x4 zero = {0.f, 0.f, 0.f, 0.f};
#pragma unroll
  for (int tm = 0; tm < 4; tm++)
#pragma unroll
    for (int tn = 0; tn < 4; tn++) acc[tm][tn] = zero;

  gemm_tile(A, Dd, Bp, Dd, 0, Dd, shmem, acc);

  // Unnormalized exp (|s/32| << 88 so fp32 exp safe without max-subtraction).
  u16* out = sc + (size_t)b * Ss * Ss;
  float* lr = lsum + (size_t)b * Ss;
  const int lane = tid & 63, wave = tid >> 6;
  const int quad = lane >> 4, r16 = lane & 15;
  const int wm = (wave & 1) * 64, wn = (wave >> 1) * 64;
#pragma unroll
  for (int tm = 0; tm < 4; tm++) {
    float psum[4] = {0.f, 0.f, 0.f, 0.f};  // per r, summed over tn
#pragma unroll
    for (int tn = 0; tn < 4; tn++) {
      int rr = it * BM + wm + tm * 16 + quad * 4;
      int cc = jt * BN + wn + tn * 16 + r16;
#pragma unroll
      for (int r = 0; r < 4; r++) {
        float p = 0.f;
        u16 h = 0;
        if (cc <= rr + r) {
          h = f2bf(__expf(acc[tm][tn][r] * 0.03125f));
          p = bf2f(h);  // sum the bf16-rounded value (matches stored numerator)
        }
        out[(size_t)(rr + r) * Ss + cc] = h;
        psum[r] += p;
      }
    }
#pragma unroll
    for (int r = 0; r < 4; r++) {
      float s = psum[r];
      s += __shfl_xor(s, 1);
      s += __shfl_xor(s, 2);
      s += __shfl_xor(s, 4);
      s += __shfl_xor(s, 8);
      if (r16 == 0) {
        int row = it * BM + wm + tm * 16 + quad * 4 + r;
        atomicAdd(&lr[row], s);
      }
    }
  }
}

// ---------------- PV: O[q,e] = (1/l[q]) * sum_k sc[q,k] Vt[e,k] ----------------
// XCD-grouped schedule: xcd=idx&7, slot=idx>>3; qp=slot>>3 (0..7), col=slot&7.
// b=qp&3, it=(qp>>2)?15-xcd:xcd. The 8 col-tiles of one (b,it) are consecutive
// slots on ONE XCD -> sc A-panel fetched ~once from HBM (not 8x) and vt[b]
// reused in that XCD's L2. Each XCD gets its {xcd, 15-xcd} -> uniform 17
// tile-K per XCD regardless of block->CU pairing granularity.
__global__ __launch_bounds__(256) void pv_gemm(const u16* __restrict__ sc,
                                               const u16* __restrict__ vt,
                                               const float* __restrict__ lsum,
                                               float* __restrict__ out) {
  __shared__ __align__(16) u16 shmem[16384];
  const int idx = blockIdx.x;            // 0..511
  const int xcd = idx & 7, slot = idx >> 3;
  const int qp = slot >> 3, col = slot & 7;
  const int b = qp & 3;
  const int it = (qp >> 2) ? (15 - xcd) : xcd;
  const int row0 = it * BM;
  const int col0 = col * BN;             // N = 1024
  const u16* A  = sc + (size_t)b * Ss * Ss + (size_t)row0 * Ss;
  const u16* Bp = vt + (size_t)b * Dd * Ss + (size_t)col0 * Ss;
  f32x4 acc[4][4];
  const f32x4 zero = {0.f, 0.f, 0.f, 0.f};
#pragma unroll
  for (int tm = 0; tm < 4; tm++)
#pragma unroll
    for (int tn = 0; tn < 4; tn++) acc[tm][tn] = zero;

  // causal: P[q,k]==0 for k > q (incl. zero-filled diag tile), K-loop clipped
  gemm_tile(A, Ss, Bp, Ss, 0, row0 + BM, shmem, acc);

  float* o = out + (size_t)b * Ss * Dd;
  const float* lr = lsum + (size_t)b * Ss;
  const int lane = threadIdx.x & 63, wave = threadIdx.x >> 6;
  const int quad = lane >> 4, r16 = lane & 15;
  const int wm = (wave & 1) * 64, wn = (wave >> 1) * 64;
#pragma unroll
  for (int tm = 0; tm < 4; tm++) {
    int rbase = row0 + wm + tm * 16 + quad * 4;
    float s0 = 1.f / lr[rbase], s1 = 1.f / lr[rbase + 1];
    float s2 = 1.f / lr[rbase + 2], s3 = 1.f / lr[rbase + 3];
#pragma unroll
    for (int tn = 0; tn < 4; tn++) {
      int cc = col0 + wn + tn * 16 + r16;
      o[(size_t)(rbase + 0) * Dd + cc] = acc[tm][tn][0] * s0;
      o[(size_t)(rbase + 1) * Dd + cc] = acc[tm][tn][1] * s1;
      o[(size_t)(rbase + 2) * Dd + cc] = acc[tm][tn][2] * s2;
      o[(size_t)(rbase + 3) * Dd + cc] = acc[tm][tn][3] * s3;
    }
  }
}

// ---------------- launch ----------------
// Workspace layout (bytes), total 106,987,520 (~102 MB):
//   qkv : [0, 50331648)           q,k,v bf16, each 16 MB
//   sc  : [50331648, 83886080)    exp-scores bf16, 32 MB
//   xb  : [83886080, 100663296)   x bf16 16 MB; REUSED as vt after qkv_gemm
//   wb  : [100663296, 106954752)  wq|wk|wv bf16, 6 MB
//   lsum: [106954752, 106987520)  per-row sum fp32, 32 KB (zeroed by cast_all)
extern "C" void kernel_launch(void* const* d_in, const int* in_sizes, int n_in,
                              void* d_out, int out_size, void* d_ws, size_t ws_size,
                              hipStream_t stream) {
  const float* x  = (const float*)d_in[0];
  const float* wq = (const float*)d_in[1];
  const float* wk = (const float*)d_in[2];
  const float* wv = (const float*)d_in[3];
  float* out = (float*)d_out;
  char* ws = (char*)d_ws;
  if (ws_size < 106987520u) return;  // clean fail rather than OOB corruption

  u16* qkv  = (u16*)(ws);
  u16* sc   = (u16*)(ws + 50331648u);
  u16* xb   = (u16*)(ws + 83886080u);
  u16* vt   = xb;  // alias: x dead after qkv_gemm
  u16* wb   = (u16*)(ws + 100663296u);
  float* lsum = (float*)(ws + 106954752u);

  const size_t nQ = (size_t)Bb * Ss * Dd;  // 8388608

  cast_all<<<2816, 256, 0, stream>>>(x, wq, wk, wv, xb, wb, lsum);
  qkv_gemm<<<1536, 256, 0, stream>>>(xb, wb, qkv);
  scores_fused<<<1024, 256, 0, stream>>>(qkv, qkv + nQ, qkv + 2 * nQ, sc, vt, lsum);
  pv_gemm<<<512, 256, 0, stream>>>(sc, vt, lsum, out);
}